// Round 11
// baseline (48.357 us; speedup 1.0000x reference)
//
#include <hip/hip_runtime.h>
#include <hip/hip_bf16.h>

#define HIDDEN 64
#define BATCH 2048
#define SFULL 1024
#define SM1 1023
#define LN_CLAMP -23.025850929940457f  // ln(1e-10)
#define PAIRS 8                        // 16 sp per block (grid.y = 64)

typedef __bf16 bf16x8 __attribute__((ext_vector_type(8)));
typedef float  f32x4  __attribute__((ext_vector_type(4)));
typedef float  f32x16 __attribute__((ext_vector_type(16)));

// Force a value into arch VGPRs ("v" class). No code emitted if RA complies
// by allocating the producer's destination there directly.
#define PIN_V(x) asm volatile("" : "+v"(x))

// Fragment cache: 22 units of [64 lanes][16B].
//  u 0,1   : a1[mt]        (bf16x8)   layer-1 A (bias folded at k=3)
//  u 2..9  : a2[mt][c]     (u = 2 + mt*4 + c)
//  u 10..13: a3[c]
//  u 14..21: c2init[mt] regs 4q..4q+3 (u = 14 + mt*4 + q, f32x4)
#define FRAG_UNITS 22

// sigma: D-row -> hidden idx so D frag == next mfma's B frag per-lane.
// Hardware-verified in R7-R9 (absmax 0.0).
__device__ __forceinline__ int sig(int rg) {
    return 16 * ((rg >> 3) & 3) + 8 * ((rg >> 2) & 1) + (rg & 3) + 4 * (rg >> 5);
}

// ---- truncating bf16 pack: {bf16(lo), bf16(hi)} in one dword -------------
__device__ __forceinline__ unsigned pkt(float lo, float hi) {
    return __builtin_amdgcn_perm(__float_as_uint(hi), __float_as_uint(lo), 0x07060302u);
}
__device__ __forceinline__ unsigned rp2(float lo, float hi) {
    return pkt(fmaxf(lo, 0.0f), fmaxf(hi, 0.0f));  // relu + pack: 3 instrs/pair
}

// relu+pack two f32x16 D-frags into 4 B-frags (layout verified R7):
__device__ __forceinline__ void relu_pack4(const f32x16 lo, const f32x16 hi, bf16x8* out) {
#pragma unroll
    for (int c = 0; c < 4; ++c) {
        union { unsigned u[4]; bf16x8 v; } r;
        r.u[0] = rp2(lo[4 * c + 0], lo[4 * c + 1]);
        r.u[1] = rp2(lo[4 * c + 2], lo[4 * c + 3]);
        r.u[2] = rp2(hi[4 * c + 0], hi[4 * c + 1]);
        r.u[3] = rp2(hi[4 * c + 2], hi[4 * c + 3]);
        out[c] = r.v;
    }
}

// feature B-frag {xt, t, x0, 1, ...} (elems k>=4 multiply A=0)
__device__ __forceinline__ bf16x8 featpk(float xt, float t, float x0) {
    union { unsigned u[4]; bf16x8 v; } r;
    r.u[0] = pkt(xt, t);
    r.u[1] = pkt(x0, 1.0f);
    r.u[2] = r.u[0]; r.u[3] = r.u[1];
    return r.v;
}

// ---------------- Kernel 0: one-time fragment gather (1 block) -------------
__global__ __launch_bounds__(256) void frag_setup_kernel(
    const float* __restrict__ W1, const float* __restrict__ b1,
    const float* __restrict__ W2, const float* __restrict__ b2,
    const float* __restrict__ Wout, char* __restrict__ F)
{
    const int l    = threadIdx.x & 63;
    const int wv   = threadIdx.x >> 6;
    const int pcol = l & 31;
    const int hi   = l >> 5;

    if (wv == 0) {
#pragma unroll
        for (int mt = 0; mt < 2; ++mt) {
            const int hout = sig(32 * mt + pcol);
            bf16x8 v;
#pragma unroll
            for (int j = 0; j < 8; ++j) {
                const int k = 8 * hi + j;
                v[j] = (k < 3) ? (__bf16)W1[k * 64 + hout]
                     : (k == 3) ? (__bf16)b1[hout] : (__bf16)0.0f;
            }
            *(bf16x8*)(F + ((mt * 64 + l) << 4)) = v;
        }
#pragma unroll
        for (int c = 0; c < 4; ++c) {
            bf16x8 v;
#pragma unroll
            for (int j = 0; j < 8; ++j) {
                const int k = 16 * c + 8 * hi + j;
                v[j] = (pcol < 3) ? (__bf16)Wout[k * 3 + pcol] : (__bf16)0.0f;
            }
            *(bf16x8*)(F + (((10 + c) * 64 + l) << 4)) = v;
        }
    } else if (wv == 1 || wv == 2) {
        const int mt = wv - 1;
        const int hout = sig(32 * mt + pcol);
#pragma unroll
        for (int c = 0; c < 4; ++c) {
            bf16x8 v;
#pragma unroll
            for (int j = 0; j < 8; ++j)
                v[j] = (__bf16)W2[(16 * c + 8 * hi + j) * 64 + hout];
            *(bf16x8*)(F + (((2 + mt * 4 + c) * 64 + l) << 4)) = v;
        }
    } else {
#pragma unroll
        for (int mt = 0; mt < 2; ++mt)
#pragma unroll
            for (int q = 0; q < 4; ++q) {
                f32x4 v;
#pragma unroll
                for (int rr = 0; rr < 4; ++rr) {
                    const int r = 4 * q + rr;
                    v[rr] = b2[16 * (r >> 2) + 8 * hi + (r & 3) + 4 * mt];
                }
                *(f32x4*)(F + (((14 + mt * 4 + q) * 64 + l) << 4)) = v;
            }
    }
}

// ---------------- Kernel 1: identical to R9 except VGPR pins ---------------
__global__ __launch_bounds__(256, 2) void mlp_z_kernel(
    const float* __restrict__ ys,    // (B, S, 2)
    const char* __restrict__ F,      // fragment cache
    const float* __restrict__ bout,  // (3)
    float* __restrict__ z)           // (SM1, BATCH)
{
    const int l    = threadIdx.x & 63;
    const int wv   = threadIdx.x >> 6;
    const int pcol = l & 31;

    const int b   = (blockIdx.x * 4 + wv) * 32 + pcol;
    const int sp0 = blockIdx.y * (2 * PAIRS);
    const int omax = (SFULL - 1) - sp0;

    // ---- coalesced fragment loads (L2-hot) ----
    bf16x8 a1[2], a2[2][4], a3[4];
    f32x16 c2init[2];
#pragma unroll
    for (int mt = 0; mt < 2; ++mt) {
        a1[mt] = *(const bf16x8*)(F + ((mt * 64 + l) << 4));
#pragma unroll
        for (int c = 0; c < 4; ++c)
            a2[mt][c] = *(const bf16x8*)(F + (((2 + mt * 4 + c) * 64 + l) << 4));
#pragma unroll
        for (int q = 0; q < 4; ++q) {
            const f32x4 v = *(const f32x4*)(F + (((14 + mt * 4 + q) * 64 + l) << 4));
            c2init[mt][4 * q + 0] = v[0]; c2init[mt][4 * q + 1] = v[1];
            c2init[mt][4 * q + 2] = v[2]; c2init[mt][4 * q + 3] = v[3];
        }
    }
#pragma unroll
    for (int c = 0; c < 4; ++c)
        a3[c] = *(const bf16x8*)(F + (((10 + c) * 64 + l) << 4));

    const float bo0 = bout[0], bo1 = bout[1], bo2 = bout[2];

    f32x16 zero16;
#pragma unroll
    for (int i = 0; i < 16; ++i) zero16[i] = 0.0f;

    const float2* base2 = reinterpret_cast<const float2*>(ys) + ((size_t)b * SFULL + sp0);
    float* zb = z + (size_t)sp0 * BATCH + b;

    float2 qa = base2[0];
    float2 qb = base2[min(1, omax)];
    float2 qc = base2[min(2, omax)];

    for (int it = 0; it < PAIRS; ++it) {
        const float2 nb = base2[min(2 * it + 3, omax)];
        const float2 nc = base2[min(2 * it + 4, omax)];

        const float x0a = qa.y, ta = qb.x, xta = qb.y;   // chain A: sp0+2it
        const float x0b = qb.y, tb = qc.x, xtb = qc.y;   // chain B: sp0+2it+1

        const bf16x8 f0a = featpk(xta, ta, x0a);
        const bf16x8 f0b = featpk(xtb, tb, x0b);

        // ---- layer 1 ----
        f32x16 a1_0 = __builtin_amdgcn_mfma_f32_32x32x16_bf16(a1[0], f0a, zero16, 0, 0, 0);
        f32x16 a1_1 = __builtin_amdgcn_mfma_f32_32x32x16_bf16(a1[1], f0a, zero16, 0, 0, 0);
        f32x16 b1_0 = __builtin_amdgcn_mfma_f32_32x32x16_bf16(a1[0], f0b, zero16, 0, 0, 0);
        f32x16 b1_1 = __builtin_amdgcn_mfma_f32_32x32x16_bf16(a1[1], f0b, zero16, 0, 0, 0);
        PIN_V(a1_0); PIN_V(a1_1); PIN_V(b1_0); PIN_V(b1_1);

        bf16x8 h1a[4], h1b[4];
        relu_pack4(a1_0, a1_1, h1a);
        relu_pack4(b1_0, b1_1, h1b);

        // ---- layer 2 ----
        f32x16 a2_0 = __builtin_amdgcn_mfma_f32_32x32x16_bf16(a2[0][0], h1a[0], c2init[0], 0, 0, 0);
        f32x16 a2_1 = __builtin_amdgcn_mfma_f32_32x32x16_bf16(a2[1][0], h1a[0], c2init[1], 0, 0, 0);
        f32x16 b2_0 = __builtin_amdgcn_mfma_f32_32x32x16_bf16(a2[0][0], h1b[0], c2init[0], 0, 0, 0);
        f32x16 b2_1 = __builtin_amdgcn_mfma_f32_32x32x16_bf16(a2[1][0], h1b[0], c2init[1], 0, 0, 0);
#pragma unroll
        for (int c = 1; c < 4; ++c) {
            a2_0 = __builtin_amdgcn_mfma_f32_32x32x16_bf16(a2[0][c], h1a[c], a2_0, 0, 0, 0);
            a2_1 = __builtin_amdgcn_mfma_f32_32x32x16_bf16(a2[1][c], h1a[c], a2_1, 0, 0, 0);
            b2_0 = __builtin_amdgcn_mfma_f32_32x32x16_bf16(a2[0][c], h1b[c], b2_0, 0, 0, 0);
            b2_1 = __builtin_amdgcn_mfma_f32_32x32x16_bf16(a2[1][c], h1b[c], b2_1, 0, 0, 0);
        }
        PIN_V(a2_0); PIN_V(a2_1); PIN_V(b2_0); PIN_V(b2_1);

        bf16x8 h2a[4], h2b[4];
        relu_pack4(a2_0, a2_1, h2a);
        relu_pack4(b2_0, b2_1, h2b);

        // ---- layer 3 (accs may stay in AGPRs; only 3 elems read) ----
        f32x16 a3acc = __builtin_amdgcn_mfma_f32_32x32x16_bf16(a3[0], h2a[0], zero16, 0, 0, 0);
        f32x16 b3acc = __builtin_amdgcn_mfma_f32_32x32x16_bf16(a3[0], h2b[0], zero16, 0, 0, 0);
#pragma unroll
        for (int c = 1; c < 4; ++c) {
            a3acc = __builtin_amdgcn_mfma_f32_32x32x16_bf16(a3[c], h2a[c], a3acc, 0, 0, 0);
            b3acc = __builtin_amdgcn_mfma_f32_32x32x16_bf16(a3[c], h2b[c], b3acc, 0, 0, 0);
        }

        // epilogue (hi=0 lanes hold rows 0..2)
        const float ca0 = a3acc[0] + bo0, ca1 = a3acc[1] + bo1, ca2 = a3acc[2] + bo2;
        const float cb0 = b3acc[0] + bo0, cb1 = b3acc[1] + bo1, cb2 = b3acc[2] + bo2;
        const float zva = fmaf(ca2, fmaf(4.0f * xta, xta, -2.0f), fmaf(ca1, xta + xta, ca0));
        const float zvb = fmaf(cb2, fmaf(4.0f * xtb, xtb, -2.0f), fmaf(cb1, xtb + xtb, cb0));

        if (l < 32) {
            zb[0] = zva;
            if (sp0 + 2 * it + 1 < SM1)  // only skips (by=63, it=7) second sp
                zb[BATCH] = zvb;
        }
        zb += 2 * BATCH;

        qa = qc; qb = nb; qc = nc;
    }
}

// ---------------- reduction helpers ----------------
__device__ __forceinline__ float blk_reduce_max(float v) {
    __shared__ float s[4];
#pragma unroll
    for (int off = 32; off >= 1; off >>= 1) v = fmaxf(v, __shfl_xor(v, off));
    if ((threadIdx.x & 63) == 0) s[threadIdx.x >> 6] = v;
    __syncthreads();
    v = fmaxf(fmaxf(s[0], s[1]), fmaxf(s[2], s[3]));
    __syncthreads();
    return v;
}

__device__ __forceinline__ float blk_reduce_sum(float v) {
    __shared__ float s[4];
#pragma unroll
    for (int off = 32; off >= 1; off >>= 1) v += __shfl_xor(v, off);
    if ((threadIdx.x & 63) == 0) s[threadIdx.x >> 6] = v;
    __syncthreads();
    v = (s[0] + s[1]) + (s[2] + s[3]);
    __syncthreads();
    return v;
}

// ---------------- Kernel 2: per-column softmax + logclip sum ----------------
__global__ __launch_bounds__(256) void col_softmax_kernel(
    const float* __restrict__ z, float* __restrict__ colsum)
{
    const int sp = blockIdx.x;
    const int tid = threadIdx.x;
    const float* col = z + (size_t)sp * BATCH;

    float vals[8];
    float m = -3.4e38f;
#pragma unroll
    for (int i = 0; i < 8; ++i) {
        vals[i] = col[tid + 256 * i];
        m = fmaxf(m, vals[i]);
    }
    const float M = blk_reduce_max(m);

    float se = 0.0f;
#pragma unroll
    for (int i = 0; i < 8; ++i) se += __expf(vals[i] - M);
    const float S = blk_reduce_sum(se);
    const float L = __logf(S);

    float acc = 0.0f;
#pragma unroll
    for (int i = 0; i < 8; ++i) acc += fmaxf(vals[i] - M - L, LN_CLAMP);
    const float T = blk_reduce_sum(acc);
    if (tid == 0) colsum[sp] = T;
}

// ---------------- Kernel 3: final scalar ----------------
__global__ __launch_bounds__(256) void final_reduce_kernel(
    const float* __restrict__ colsum, float* __restrict__ out)
{
    const int tid = threadIdx.x;
    float v = 0.0f;
    for (int i = tid; i < SM1; i += 256) v += colsum[i];
    const float T = blk_reduce_sum(v);
    if (tid == 0) out[0] = T / (float)BATCH;
}

extern "C" void kernel_launch(void* const* d_in, const int* in_sizes, int n_in,
                              void* d_out, int out_size, void* d_ws, size_t ws_size,
                              hipStream_t stream) {
    const float* ys   = (const float*)d_in[0];
    const float* W1   = (const float*)d_in[1];
    const float* b1   = (const float*)d_in[2];
    const float* W2   = (const float*)d_in[3];
    const float* b2   = (const float*)d_in[4];
    const float* Wout = (const float*)d_in[5];
    const float* bout = (const float*)d_in[6];
    float* out = (float*)d_out;

    float* z      = (float*)d_ws;                         // SM1*BATCH floats
    float* colsum = z + (size_t)SM1 * BATCH;              // SM1 floats
    size_t fo = ((size_t)SM1 * BATCH + SM1) * sizeof(float);
    fo = (fo + 15) & ~(size_t)15;
    char* F = (char*)d_ws + fo;                           // 22*64*16 = 22.5 KB

    frag_setup_kernel<<<1, 256, 0, stream>>>(W1, b1, W2, b2, Wout, F);
    dim3 grid1(16, 64);  // 16*4 waves * 32 pts = 2048 b ; 64*16 = 1024 sp slots
    mlp_z_kernel<<<grid1, 256, 0, stream>>>(ys, F, bout, z);
    col_softmax_kernel<<<SM1, 256, 0, stream>>>(z, colsum);
    final_reduce_kernel<<<1, 256, 0, stream>>>(colsum, out);
}

// Round 12
// 42.825 us; speedup vs baseline: 1.1292x; 1.1292x over previous
//
#include <hip/hip_runtime.h>
#include <hip/hip_bf16.h>

#define HIDDEN 64
#define BATCH 2048
#define SFULL 1024
#define SM1 1023
#define LN_CLAMP -23.025850929940457f  // ln(1e-10)
#define SP_PER 16                      // grid.y = 64 -> 64*16 = 1024 sp slots

typedef __bf16 bf16x8 __attribute__((ext_vector_type(8)));
typedef float  f32x4  __attribute__((ext_vector_type(4)));
typedef float  f32x16 __attribute__((ext_vector_type(16)));
typedef short  s16x2  __attribute__((ext_vector_type(2)));

// Fragment cache: 16 units of [64 lanes][16B].
//  u 0,1   : a1[mt]     layer-1 A (b1 folded at k=3)
//  u 2..9  : a2[mt][c]  (u = 2 + mt*4 + c)
//  u 10..13: a3[c]
//  u 14,15 : a2b[mt]    bias frag: A[row][k_local=0] = b2[sig(32mt+row)]
#define FRAG_UNITS 16

// sigma: D-row -> hidden idx so D frag == next mfma's B frag per-lane.
// Hardware-verified R7-R10 (absmax 0.0).
__device__ __forceinline__ int sig(int rg) {
    return 16 * ((rg >> 3) & 3) + 8 * ((rg >> 2) & 1) + (rg & 3) + 4 * (rg >> 5);
}

// truncating bf16 pack of 2 f32 (RTZ: take high 16 bits of each)
__device__ __forceinline__ unsigned pkt(float lo, float hi) {
    return __builtin_amdgcn_perm(__float_as_uint(hi), __float_as_uint(lo), 0x07060302u);
}
// packed relu on 2 bf16: int16 max-with-0 == relu for sign-magnitude bf16
__device__ __forceinline__ unsigned rp(unsigned x) {
    s16x2 v = __builtin_bit_cast(s16x2, x);
    s16x2 z = {0, 0};
    v = __builtin_elementwise_max(v, z);
    return __builtin_bit_cast(unsigned, v);
}

// pack+relu two f32x16 D-frags into 4 B-frags (layout verified R7): 2 instr/pair
__device__ __forceinline__ void relu_pack4(const f32x16 lo, const f32x16 hi, bf16x8* out) {
#pragma unroll
    for (int c = 0; c < 4; ++c) {
        union { unsigned u[4]; bf16x8 v; } r;
        r.u[0] = rp(pkt(lo[4 * c + 0], lo[4 * c + 1]));
        r.u[1] = rp(pkt(lo[4 * c + 2], lo[4 * c + 3]));
        r.u[2] = rp(pkt(hi[4 * c + 0], hi[4 * c + 1]));
        r.u[3] = rp(pkt(hi[4 * c + 2], hi[4 * c + 3]));
        out[c] = r.v;
    }
}

// feature B-frag {xt, t, x0, 1, ...} (elems k>=4 multiply A=0)
__device__ __forceinline__ bf16x8 featpk(float xt, float t, float x0) {
    union { unsigned u[4]; bf16x8 v; } r;
    r.u[0] = pkt(xt, t);
    r.u[1] = pkt(x0, 1.0f);
    r.u[2] = r.u[0]; r.u[3] = r.u[1];
    return r.v;
}

// ---------------- Kernel 0: one-time fragment gather (1 block) -------------
__global__ __launch_bounds__(256) void frag_setup_kernel(
    const float* __restrict__ W1, const float* __restrict__ b1,
    const float* __restrict__ W2, const float* __restrict__ b2,
    const float* __restrict__ Wout, char* __restrict__ F)
{
    const int l    = threadIdx.x & 63;
    const int wv   = threadIdx.x >> 6;
    const int pcol = l & 31;
    const int hi   = l >> 5;

    if (wv == 0) {
        // a1[mt] + a3[c]
#pragma unroll
        for (int mt = 0; mt < 2; ++mt) {
            const int hout = sig(32 * mt + pcol);
            bf16x8 v;
#pragma unroll
            for (int j = 0; j < 8; ++j) {
                const int k = 8 * hi + j;
                v[j] = (k < 3) ? (__bf16)W1[k * 64 + hout]
                     : (k == 3) ? (__bf16)b1[hout] : (__bf16)0.0f;
            }
            *(bf16x8*)(F + ((mt * 64 + l) << 4)) = v;
        }
#pragma unroll
        for (int c = 0; c < 4; ++c) {
            bf16x8 v;
#pragma unroll
            for (int j = 0; j < 8; ++j) {
                const int k = 16 * c + 8 * hi + j;
                v[j] = (pcol < 3) ? (__bf16)Wout[k * 3 + pcol] : (__bf16)0.0f;
            }
            *(bf16x8*)(F + (((10 + c) * 64 + l) << 4)) = v;
        }
    } else if (wv == 1 || wv == 2) {
        // a2[mt][c]
        const int mt = wv - 1;
        const int hout = sig(32 * mt + pcol);
#pragma unroll
        for (int c = 0; c < 4; ++c) {
            bf16x8 v;
#pragma unroll
            for (int j = 0; j < 8; ++j)
                v[j] = (__bf16)W2[(16 * c + 8 * hi + j) * 64 + hout];
            *(bf16x8*)(F + (((2 + mt * 4 + c) * 64 + l) << 4)) = v;
        }
    } else {
        // a2b[mt]: bias frag; only k_local==0 (hi==0, j==0) nonzero
#pragma unroll
        for (int mt = 0; mt < 2; ++mt) {
            const int hout = sig(32 * mt + pcol);
            bf16x8 v;
#pragma unroll
            for (int j = 0; j < 8; ++j)
                v[j] = (hi == 0 && j == 0) ? (__bf16)b2[hout] : (__bf16)0.0f;
            *(bf16x8*)(F + (((14 + mt) * 64 + l) << 4)) = v;
        }
    }
}

// ---------------- Kernel 1: 3-layer MLP, 32x32x16 MFMA, single chain -------
// grid (16, 64), block 256 (4 waves), __launch_bounds__(256,3) -> 3 waves/SIMD.
// Wave w owns 32 points b = (blockIdx.x*4+w)*32 + (lane&31); 16 sp iterations.
// Per sp (16 MFMA): L1 2 -> pack(2 instr/pair) -> L2 2 bias + 2x4 chain ->
// pack -> L3 serial 4 -> epilogue rows 0..2 (hi=0 lanes) -> store.
__global__ __launch_bounds__(256, 3) void mlp_z_kernel(
    const float* __restrict__ ys,    // (B, S, 2)
    const char* __restrict__ F,      // fragment cache
    const float* __restrict__ bout,  // (3)
    float* __restrict__ z)           // (SM1, BATCH)
{
    const int l    = threadIdx.x & 63;
    const int wv   = threadIdx.x >> 6;
    const int pcol = l & 31;
    const int hi   = l >> 5;

    const int b   = (blockIdx.x * 4 + wv) * 32 + pcol;
    const int sp0 = blockIdx.y * SP_PER;
    const int omax = (SFULL - 1) - sp0;

    // ---- coalesced fragment loads (L2-hot) ----
    bf16x8 a1[2], a2[2][4], a3[4], a2b[2];
#pragma unroll
    for (int mt = 0; mt < 2; ++mt) {
        a1[mt]  = *(const bf16x8*)(F + ((mt * 64 + l) << 4));
        a2b[mt] = *(const bf16x8*)(F + (((14 + mt) * 64 + l) << 4));
#pragma unroll
        for (int c = 0; c < 4; ++c)
            a2[mt][c] = *(const bf16x8*)(F + (((2 + mt * 4 + c) * 64 + l) << 4));
    }
#pragma unroll
    for (int c = 0; c < 4; ++c)
        a3[c] = *(const bf16x8*)(F + (((10 + c) * 64 + l) << 4));

    // B_one: B[k_local][*] = 1 at k_local==0 -> hi==0 lanes, halfword 0
    bf16x8 Bone;
    {
        union { unsigned u[4]; bf16x8 v; } r;
        r.u[0] = (hi == 0) ? 0x3F80u : 0u;  // bf16(1.0)
        r.u[1] = 0u; r.u[2] = 0u; r.u[3] = 0u;
        Bone = r.v;
    }

    const float bo0 = bout[0], bo1 = bout[1], bo2 = bout[2];

    f32x16 zero16;
#pragma unroll
    for (int i = 0; i < 16; ++i) zero16[i] = 0.0f;

    const float2* base2 = reinterpret_cast<const float2*>(ys) + ((size_t)b * SFULL + sp0);
    float* zb = z + (size_t)sp0 * BATCH + b;

    float2 q0 = base2[0];
    float2 q1 = base2[min(1, omax)];
    float2 qn = base2[min(2, omax)];

    for (int it = 0; it < SP_PER; ++it) {
        const float2 qn2 = base2[min(it + 3, omax)];  // prefetch

        const float x0 = q0.y, t = q1.x, xt = q1.y;
        const bf16x8 f0 = featpk(xt, t, x0);

        // ---- layer 1 (b1 folded) ----
        f32x16 acc1_0 = __builtin_amdgcn_mfma_f32_32x32x16_bf16(a1[0], f0, zero16, 0, 0, 0);
        f32x16 acc1_1 = __builtin_amdgcn_mfma_f32_32x32x16_bf16(a1[1], f0, zero16, 0, 0, 0);

        // L2 bias mfmas first: independent of h1, hide under L1/pack
        f32x16 acc2_0 = __builtin_amdgcn_mfma_f32_32x32x16_bf16(a2b[0], Bone, zero16, 0, 0, 0);
        f32x16 acc2_1 = __builtin_amdgcn_mfma_f32_32x32x16_bf16(a2b[1], Bone, zero16, 0, 0, 0);

        bf16x8 h1f[4];
        relu_pack4(acc1_0, acc1_1, h1f);

        // ---- layer 2 ----
#pragma unroll
        for (int c = 0; c < 4; ++c) {
            acc2_0 = __builtin_amdgcn_mfma_f32_32x32x16_bf16(a2[0][c], h1f[c], acc2_0, 0, 0, 0);
            acc2_1 = __builtin_amdgcn_mfma_f32_32x32x16_bf16(a2[1][c], h1f[c], acc2_1, 0, 0, 0);
        }

        bf16x8 h2f[4];
        relu_pack4(acc2_0, acc2_1, h2f);

        // ---- layer 3 (serial 4; only rows 0..2 consumed) ----
        f32x16 acc3 = __builtin_amdgcn_mfma_f32_32x32x16_bf16(a3[0], h2f[0], zero16, 0, 0, 0);
#pragma unroll
        for (int c = 1; c < 4; ++c)
            acc3 = __builtin_amdgcn_mfma_f32_32x32x16_bf16(a3[c], h2f[c], acc3, 0, 0, 0);

        // epilogue (hi=0 lanes hold rows 0..2)
        const float c0 = acc3[0] + bo0;
        const float c1 = acc3[1] + bo1;
        const float c2 = acc3[2] + bo2;
        const float zv = fmaf(c2, fmaf(4.0f * xt, xt, -2.0f), fmaf(c1, xt + xt, c0));

        if (l < 32 && sp0 + it < SM1)
            zb[(size_t)it * BATCH] = zv;

        q0 = q1; q1 = qn; qn = qn2;
    }
}

// ---------------- reduction helpers ----------------
__device__ __forceinline__ float blk_reduce_max(float v) {
    __shared__ float s[4];
#pragma unroll
    for (int off = 32; off >= 1; off >>= 1) v = fmaxf(v, __shfl_xor(v, off));
    if ((threadIdx.x & 63) == 0) s[threadIdx.x >> 6] = v;
    __syncthreads();
    v = fmaxf(fmaxf(s[0], s[1]), fmaxf(s[2], s[3]));
    __syncthreads();
    return v;
}

__device__ __forceinline__ float blk_reduce_sum(float v) {
    __shared__ float s[4];
#pragma unroll
    for (int off = 32; off >= 1; off >>= 1) v += __shfl_xor(v, off);
    if ((threadIdx.x & 63) == 0) s[threadIdx.x >> 6] = v;
    __syncthreads();
    v = (s[0] + s[1]) + (s[2] + s[3]);
    __syncthreads();
    return v;
}

// ---------------- Kernel 2: per-column softmax + logclip sum ----------------
__global__ __launch_bounds__(256) void col_softmax_kernel(
    const float* __restrict__ z, float* __restrict__ colsum)
{
    const int sp = blockIdx.x;
    const int tid = threadIdx.x;
    const float* col = z + (size_t)sp * BATCH;

    float vals[8];
    float m = -3.4e38f;
#pragma unroll
    for (int i = 0; i < 8; ++i) {
        vals[i] = col[tid + 256 * i];
        m = fmaxf(m, vals[i]);
    }
    const float M = blk_reduce_max(m);

    float se = 0.0f;
#pragma unroll
    for (int i = 0; i < 8; ++i) se += __expf(vals[i] - M);
    const float S = blk_reduce_sum(se);
    const float L = __logf(S);

    float acc = 0.0f;
#pragma unroll
    for (int i = 0; i < 8; ++i) acc += fmaxf(vals[i] - M - L, LN_CLAMP);
    const float T = blk_reduce_sum(acc);
    if (tid == 0) colsum[sp] = T;
}

// ---------------- Kernel 3: final scalar ----------------
__global__ __launch_bounds__(256) void final_reduce_kernel(
    const float* __restrict__ colsum, float* __restrict__ out)
{
    const int tid = threadIdx.x;
    float v = 0.0f;
    for (int i = tid; i < SM1; i += 256) v += colsum[i];
    const float T = blk_reduce_sum(v);
    if (tid == 0) out[0] = T / (float)BATCH;
}

extern "C" void kernel_launch(void* const* d_in, const int* in_sizes, int n_in,
                              void* d_out, int out_size, void* d_ws, size_t ws_size,
                              hipStream_t stream) {
    const float* ys   = (const float*)d_in[0];
    const float* W1   = (const float*)d_in[1];
    const float* b1   = (const float*)d_in[2];
    const float* W2   = (const float*)d_in[3];
    const float* b2   = (const float*)d_in[4];
    const float* Wout = (const float*)d_in[5];
    const float* bout = (const float*)d_in[6];
    float* out = (float*)d_out;

    float* z      = (float*)d_ws;                         // SM1*BATCH floats
    float* colsum = z + (size_t)SM1 * BATCH;              // SM1 floats
    size_t fo = ((size_t)SM1 * BATCH + SM1) * sizeof(float);
    fo = (fo + 15) & ~(size_t)15;
    char* F = (char*)d_ws + fo;                           // 16*64*16 = 16 KB

    frag_setup_kernel<<<1, 256, 0, stream>>>(W1, b1, W2, b2, Wout, F);
    dim3 grid1(16, 64);  // 16*4 waves * 32 pts = 2048 b ; 64*16 = 1024 sp slots
    mlp_z_kernel<<<grid1, 256, 0, stream>>>(ys, F, bout, z);
    col_softmax_kernel<<<SM1, 256, 0, stream>>>(z, colsum);
    final_reduce_kernel<<<1, 256, 0, stream>>>(colsum, out);
}